// Round 5
// baseline (83.310 us; speedup 1.0000x reference)
//
#include <hip/hip_runtime.h>
#include <math.h>

// Problem constants: L=5, B=8, n=1024, d=64
#define LL 5
#define BB 8
#define NN 1024
#define DD 64
#define LB (LL * BB)      // 40 (l,b) pairs
#define KC 128            // k-rows staged per LDS chunk
#define NCH (NN / KC)     // 8 chunks
#define NTILE 10          // unique 32x32 tiles of the 128x128 gram

typedef short short8 __attribute__((ext_vector_type(8)));   // 8 bf16 = 4 VGPRs
typedef float floatx4 __attribute__((ext_vector_type(4)));  // MFMA C/D

__device__ __forceinline__ unsigned short f2bf(float f) {
    union { float f; unsigned u; } v; v.f = f;
    const unsigned u = v.u;
    return (unsigned short)((u + 0x7FFFu + ((u >> 16) & 1u)) >> 16);  // RNE
}
__device__ __forceinline__ float bf2f(unsigned short h) {
    union { unsigned u; float f; } v; v.u = ((unsigned)h) << 16; return v.f;
}

// One block per (lb, tile). tile t -> col-groups (gi, gj) of Z = [X|Y] (4 groups
// of 32 cols), category (0=xx, 1=xy, 2=yy), weight (2 for symmetric off-diag).
// Block stages 64 Z-cols (gi then gj) x K in bf16 K-major swizzled LDS chunks,
// computes the 32x32 gram tile via MFMA (4 waves split K, merge via LDS),
// centers with its own full-K column sums, squares, one atomicAdd. The gram
// never touches global memory. blockIdx -> lb = bid % 40 so all 10 tiles of an
// lb share an XCD (%8 round-robin; 40 % 8 == 0) -> redundant fetches hit L2.
__global__ __launch_bounds__(256) void gram_tiled(const float* __restrict__ X,
                                                  const float* __restrict__ Y,
                                                  float* __restrict__ Acc) {
    static const int   GIa[NTILE]  = {0, 0, 1, 2, 2, 3, 0, 0, 1, 1};
    static const int   GJa[NTILE]  = {0, 1, 1, 2, 3, 3, 2, 3, 2, 3};
    static const int   CATa[NTILE] = {0, 0, 0, 2, 2, 2, 1, 1, 1, 1};
    static const float WTa[NTILE]  = {1.f, 2.f, 1.f, 1.f, 2.f, 1.f, 1.f, 1.f, 1.f, 1.f};

    __shared__ short Zt[2][64 * KC];      // 2 x 16 KB, bf16 K-major + XOR-octet swizzle
    __shared__ float csum_scr[16][64];    // col-sum reduction scratch
    __shared__ float stot[64];            // full-K column sums (local cols)
    __shared__ float redw[4];

    const int bid = blockIdx.x;
    const int lb = bid % LB;
    const int t  = bid / LB;
    const int gi = GIa[t], gj = GJa[t], cat = CATa[t];
    const float wt = WTa[t];

    const int tid = threadIdx.x;
    const int lane = tid & 63, wv = tid >> 6;

    // Staging role: c4 in 0..15 picks a float4 column; low 8 -> group gi
    // (LDS local cols 0..31), high 8 -> group gj (local cols 32..63).
    const int c4 = tid & 15;
    const int cc = c4 & 7;
    const int isJ = c4 >> 3;
    const int grp = isJ ? gj : gi;
    const int Lc = isJ * 32 + cc * 4;                         // LDS local col base
    const float4* gp4 = (const float4*)(((grp < 2) ? X : Y) + (size_t)lb * NN * DD);
    const int colb = (grp & 1) * 8 + cc;                      // float4 col in 16-f4 row

    float csump[4] = {0.f, 0.f, 0.f, 0.f};

    // Stage chunk ch: rows [ch*KC, ch*KC+KC) of the 64 cols, fp32->bf16,
    // k-pairs packed per dword into swizzled K-major layout.
    auto stage = [&](int ch, short* buf) {
#pragma unroll
        for (int s = 0; s < 4; ++s) {
            const int kp = (tid >> 4) + s * 16;               // k-pair 0..63
            const size_t row = (size_t)ch * KC + 2 * kp;
            const float4 f0 = gp4[row * 16 + colb];
            const float4 f1 = gp4[(row + 1) * 16 + colb];
            const float a0[4] = {f0.x, f0.y, f0.z, f0.w};
            const float a1[4] = {f1.x, f1.y, f1.z, f1.w};
#pragma unroll
            for (int e = 0; e < 4; ++e) {
                const unsigned short b0 = f2bf(a0[e]), b1 = f2bf(a1[e]);
                csump[e] += bf2f(b0) + bf2f(b1);
                const int c = Lc + e;
                const int dw = c * 64 + ((((kp >> 2)) ^ (c & 15)) << 2) + (kp & 3);
                ((unsigned*)buf)[dw] = (unsigned)b0 | ((unsigned)b1 << 16);
            }
        }
    };

    floatx4 acc[2][2];
#pragma unroll
    for (int i = 0; i < 2; ++i)
#pragma unroll
        for (int j = 0; j < 2; ++j) acc[i][j] = (floatx4){0.f, 0.f, 0.f, 0.f};

    // Wave wv handles k-slice [wv*32, wv*32+32) of each chunk: 4 b128 frag
    // reads (conflict-free via swizzle) + 4 MFMA.
    auto compute = [&](const short* buf) {
        const int o = wv * 4 + (lane >> 4);
        short8 af[2], bfr[2];
#pragma unroll
        for (int i = 0; i < 2; ++i) {
            const int ca = i * 16 + (lane & 15);
            af[i] = *(const short8*)(buf + ca * 128 + ((o ^ (ca & 15)) << 3));
            const int cb = 32 + i * 16 + (lane & 15);
            bfr[i] = *(const short8*)(buf + cb * 128 + ((o ^ (cb & 15)) << 3));
        }
#pragma unroll
        for (int i = 0; i < 2; ++i)
#pragma unroll
            for (int j = 0; j < 2; ++j)
                acc[i][j] = __builtin_amdgcn_mfma_f32_16x16x32_bf16(af[i], bfr[j], acc[i][j], 0, 0, 0);
    };

    stage(0, Zt[0]);
    __syncthreads();
    for (int ch = 0; ch < NCH; ++ch) {
        if (ch + 1 < NCH) stage(ch + 1, Zt[(ch + 1) & 1]);
        compute(Zt[ch & 1]);
        __syncthreads();
    }

    // ---- epilogue: merge 4 waves' partials, col sums, center, square ----
    float* scr = (float*)Zt;   // 16 KB scratch over Zt[0] (last compute used Zt[1])
    {
        const int g = lane >> 4, cl = lane & 15;
#pragma unroll
        for (int i = 0; i < 2; ++i)
#pragma unroll
            for (int j = 0; j < 2; ++j)
#pragma unroll
                for (int r = 0; r < 4; ++r)
                    scr[wv * 1024 + (i * 16 + g * 4 + r) * 32 + (j * 16 + cl)] = acc[i][j][r];
    }
#pragma unroll
    for (int e = 0; e < 4; ++e) csum_scr[tid >> 4][Lc + e] = csump[e];
    __syncthreads();
    if (tid < 64) {
        float s = 0.f;
#pragma unroll
        for (int i = 0; i < 16; ++i) s += csum_scr[i][tid];
        stot[tid] = s;
    }
    __syncthreads();

    float sq = 0.f;
    const float inv_n = 1.0f / (float)NN;
#pragma unroll
    for (int e = 0; e < 4; ++e) {
        const int idx = tid * 4 + e;          // 0..1023 over the 32x32 tile
        const int m = idx >> 5, nn2 = idx & 31;
        const float g = scr[idx] + scr[1024 + idx] + scr[2048 + idx] + scr[3072 + idx];
        const float cv = g - stot[m] * stot[32 + nn2] * inv_n;
        sq += cv * cv;
    }
#pragma unroll
    for (int off = 32; off; off >>= 1) sq += __shfl_down(sq, off);
    if (lane == 0) redw[wv] = sq;
    __syncthreads();
    if (tid == 0)
        atomicAdd(&Acc[lb * 4 + cat], wt * (redw[0] + redw[1] + redw[2] + redw[3]));
}

// loss = mean_l( -log( mean_b( |hxy| / sqrt(vxx*vyy) ) + eps ) )
__global__ void final_kernel(const float* __restrict__ Acc, float* __restrict__ out) {
    const int tid = threadIdx.x;   // one wave
    float v = 0.0f;
    if (tid < LB) {
        const float a = Acc[tid * 4 + 0];   // vxx
        const float h = Acc[tid * 4 + 1];   // hsic
        const float b = Acc[tid * 4 + 2];   // vyy
        v = fabsf(h / (sqrtf(a) * sqrtf(b)));
    }
    v += __shfl_xor(v, 1);
    v += __shfl_xor(v, 2);
    v += __shfl_xor(v, 4);
    float loss = 0.0f;
#pragma unroll
    for (int l = 0; l < LL; ++l) {
        const float sl = __shfl(v, l * BB);
        loss += -logf(sl * (1.0f / (float)BB) + 1e-8f);
    }
    if (tid == 0) out[0] = loss * (1.0f / (float)LL);
}

extern "C" void kernel_launch(void* const* d_in, const int* in_sizes, int n_in,
                              void* d_out, int out_size, void* d_ws, size_t ws_size,
                              hipStream_t stream) {
    const float* teacher = (const float*)d_in[0];
    const float* student = (const float*)d_in[1];
    float* Acc = (float*)d_ws;   // 40 x 4 accumulators (atomics) — zero first

    hipMemsetAsync(Acc, 0, LB * 4 * sizeof(float), stream);
    gram_tiled<<<LB * NTILE, 256, 0, stream>>>(teacher, student, Acc);
    final_kernel<<<1, 64, 0, stream>>>(Acc, (float*)d_out);
}

// Round 6
// 82.618 us; speedup vs baseline: 1.0084x; 1.0084x over previous
//
#include <hip/hip_runtime.h>
#include <math.h>

// Problem constants: L=5, B=8, n=1024, d=64
#define LL 5
#define BB 8
#define NN 1024
#define DD 64
#define LB (LL * BB)       // 40 (l,b) pairs
#define SPLIT 16           // n-split: blocks per (l,b)
#define KC (NN / SPLIT)    // 64 k-rows per block
#define ZC (2 * DD)        // Z = [X | Y], 128 columns
#define NQ 3               // stored quadrants: 0=XX, 1=XY, 2=YY (YX dup skipped)

// Workspace (floats)
#define GP_SZ (LB * SPLIT * NQ * 4096)   // 7.86M floats (31.5 MB) partial quadrants
#define SP_SZ (LB * SPLIT * ZC)          // partial column sums
#define ACC_OFF (GP_SZ + SP_SZ)          // 40 x 4 accumulators

typedef short short8 __attribute__((ext_vector_type(8)));   // 8 bf16 = 4 VGPRs
typedef float floatx4 __attribute__((ext_vector_type(4)));  // MFMA C/D

__device__ __forceinline__ unsigned short f2bf(float f) {
    union { float f; unsigned u; } v; v.f = f;
    const unsigned u = v.u;
    return (unsigned short)((u + 0x7FFFu + ((u >> 16) & 1u)) >> 16);  // RNE
}
__device__ __forceinline__ float bf2f(unsigned short h) {
    union { unsigned u; float f; } v; v.u = ((unsigned)h) << 16; return v.f;
}

// LDS layout: bf16, K-major per Z-column, XOR-octet swizzle (KC=64 -> 8 octets).
// Element (c, k) at short-index: c*64 + ((k>>3) ^ (c&7))*8 + (k&7).
// Frag read = one aligned 16B ds_read_b128/lane at the conflict-free floor.
__device__ __forceinline__ short8 read_frag(const short* Zt, int tbase, int lane, int k0) {
    const int c = tbase + (lane & 15);
    const int o = (k0 >> 3) + (lane >> 4);
    return *(const short8*)(Zt + c * 64 + ((o ^ (c & 7)) << 3));
}

// Kernel 1: per-block partial gram of a 64-row slice of Z, via MFMA.
// grid (SPLIT, LB) x 256 threads (4 waves). Wave w -> quadrant (w>>1, w&1);
// the YX duplicate (w==2) is computed but not stored. Staging: 8 coalesced
// float4 loads/thread, fp32->bf16, scatter to swizzled K-major LDS.
__global__ __launch_bounds__(256) void gram_kernel(const float* __restrict__ X,
                                                   const float* __restrict__ Y,
                                                   float* __restrict__ Gp,
                                                   float* __restrict__ Sp) {
    __shared__ short Zt[ZC * KC];      // 16 KB
    __shared__ float cscr[8][ZC];      // 4 KB col-sum scratch

    const int lb = blockIdx.y, nc = blockIdx.x, tid = threadIdx.x;
    const int r0 = nc * KC;
    const float4* X4 = (const float4*)(X + (size_t)lb * NN * DD);
    const float4* Y4 = (const float4*)(Y + (size_t)lb * NN * DD);

    // ---- load: 8 float4/thread, lane-consecutive = col-consecutive ----
    const int col4 = tid & 31;           // f4-column within the 32-f4 Z row
    float4 v[8];
#pragma unroll
    for (int m = 0; m < 8; ++m) {
        const int row = (tid >> 5) + 8 * m;
        v[m] = (col4 < 16) ? X4[(size_t)(r0 + row) * 16 + col4]
                           : Y4[(size_t)(r0 + row) * 16 + (col4 - 16)];
    }

    // ---- convert + LDS scatter + bf16-consistent column sums ----
    float cs[4] = {0.f, 0.f, 0.f, 0.f};
#pragma unroll
    for (int m = 0; m < 8; ++m) {
        const int k = (tid >> 5) + 8 * m;     // chunk-local k (row)
        const float a[4] = {v[m].x, v[m].y, v[m].z, v[m].w};
#pragma unroll
        for (int e = 0; e < 4; ++e) {
            const int c = 4 * col4 + e;       // Z column 0..127
            const unsigned short b = f2bf(a[e]);
            cs[e] += bf2f(b);
            Zt[c * 64 + (((k >> 3) ^ (c & 7)) << 3) + (k & 7)] = (short)b;
        }
    }
#pragma unroll
    for (int e = 0; e < 4; ++e) cscr[tid >> 5][4 * col4 + e] = cs[e];
    __syncthreads();
    if (tid < ZC) {
        float s = 0.f;
#pragma unroll
        for (int g = 0; g < 8; ++g) s += cscr[g][tid];
        Sp[(lb * SPLIT + nc) * ZC + tid] = s;
    }

    // ---- MFMA: wave w computes its 64x64 quadrant over K=64 ----
    const int lane = tid & 63, w = tid >> 6;
    const int wr = (w >> 1) * 64, wc = (w & 1) * 64;

    floatx4 acc[4][4];
#pragma unroll
    for (int i = 0; i < 4; ++i)
#pragma unroll
        for (int j = 0; j < 4; ++j) acc[i][j] = (floatx4){0.f, 0.f, 0.f, 0.f};

#pragma unroll
    for (int k0 = 0; k0 < KC; k0 += 32) {
        short8 af[4], bfr[4];
#pragma unroll
        for (int i = 0; i < 4; ++i) af[i] = read_frag(Zt, wr + i * 16, lane, k0);
#pragma unroll
        for (int j = 0; j < 4; ++j) bfr[j] = read_frag(Zt, wc + j * 16, lane, k0);
#pragma unroll
        for (int i = 0; i < 4; ++i)
#pragma unroll
            for (int j = 0; j < 4; ++j)
                acc[i][j] = __builtin_amdgcn_mfma_f32_16x16x32_bf16(af[i], bfr[j], acc[i][j], 0, 0, 0);
    }

    // ---- store 3 unique quadrants (w==2 is the YX transpose dup) ----
    if (w != 2) {
        const int slot = (w == 0) ? 0 : (w == 1) ? 1 : 2;
        float* Gb = Gp + ((size_t)(lb * SPLIT + nc) * NQ + slot) * 4096;
        const int g = lane >> 4, cl = lane & 15;
#pragma unroll
        for (int i = 0; i < 4; ++i)
#pragma unroll
            for (int j = 0; j < 4; ++j)
#pragma unroll
                for (int r = 0; r < 4; ++r)
                    Gb[(i * 16 + g * 4 + r) * 64 + (j * 16 + cl)] = acc[i][j][r];
    }
}

// Kernel 2: sum SPLIT partials, center (Gc = G - s s^T / n), Frobenius-reduce.
// grid = LB * NQ * 4 = 480 blocks x 256 thr; block handles 1024 elements
// (one f4/thread/partial) of one quadrant; one atomicAdd per block.
__global__ __launch_bounds__(256) void reduce_kernel(const float* __restrict__ Gp,
                                                     const float* __restrict__ Sp,
                                                     float* __restrict__ Acc) {
    const int b = blockIdx.x;
    const int lb = b / (NQ * 4);
    const int rem = b % (NQ * 4);
    const int q = rem >> 2, seg = rem & 3;
    const int tid = threadIdx.x;

    __shared__ float stot[ZC];
    __shared__ float red[4];

    if (tid < ZC) {
        float s = 0.f;
#pragma unroll
        for (int sp = 0; sp < SPLIT; ++sp) s += Sp[(lb * SPLIT + sp) * ZC + tid];
        stot[tid] = s;
    }
    __syncthreads();

    const int rowbase = (q == 2) ? 64 : 0;   // quadrant rows in Z-col space
    const int colbase = (q == 0) ? 0 : 64;   // quadrant cols
    const int idx0 = seg * 1024 + tid * 4;   // element within 64x64 quadrant

    float4 g = make_float4(0.f, 0.f, 0.f, 0.f);
#pragma unroll
    for (int sp = 0; sp < SPLIT; ++sp) {
        const float4 p = *(const float4*)&Gp[((size_t)(lb * SPLIT + sp) * NQ + q) * 4096 + idx0];
        g.x += p.x; g.y += p.y; g.z += p.z; g.w += p.w;
    }
    const int row = idx0 >> 6, colb = idx0 & 63;
    const float inv_n = 1.0f / (float)NN;
    const float srow = stot[rowbase + row] * inv_n;
    const float ga[4] = {g.x, g.y, g.z, g.w};
    float sq = 0.f;
#pragma unroll
    for (int e = 0; e < 4; ++e) {
        const float cv = ga[e] - srow * stot[colbase + colb + e];
        sq += cv * cv;
    }
#pragma unroll
    for (int off = 32; off; off >>= 1) sq += __shfl_down(sq, off);
    const int wave = tid >> 6;
    if ((tid & 63) == 0) red[wave] = sq;
    __syncthreads();
    if (tid == 0)
        atomicAdd(&Acc[lb * 4 + q], red[0] + red[1] + red[2] + red[3]);
}

// Kernel 3: ratio -> loss = mean_l( -log( mean_b( |hxy|/sqrt(vxx*vyy) ) + eps ) )
__global__ void final_kernel(const float* __restrict__ Acc, float* __restrict__ out) {
    const int tid = threadIdx.x;   // one wave
    float v = 0.0f;
    if (tid < LB) {
        const float a = Acc[tid * 4 + 0];   // vxx
        const float h = Acc[tid * 4 + 1];   // hxy
        const float bb = Acc[tid * 4 + 2];  // vyy
        v = fabsf(h / (sqrtf(a) * sqrtf(bb)));
    }
    v += __shfl_xor(v, 1);
    v += __shfl_xor(v, 2);
    v += __shfl_xor(v, 4);
    float loss = 0.0f;
#pragma unroll
    for (int l = 0; l < LL; ++l) {
        const float sl = __shfl(v, l * BB);
        loss += -logf(sl * (1.0f / (float)BB) + 1e-8f);
    }
    if (tid == 0) out[0] = loss * (1.0f / (float)LL);
}

extern "C" void kernel_launch(void* const* d_in, const int* in_sizes, int n_in,
                              void* d_out, int out_size, void* d_ws, size_t ws_size,
                              hipStream_t stream) {
    const float* teacher = (const float*)d_in[0];
    const float* student = (const float*)d_in[1];
    float* ws = (float*)d_ws;
    float* Gp = ws;
    float* Sp = ws + GP_SZ;
    float* Acc = ws + ACC_OFF;

    hipMemsetAsync(Acc, 0, LB * 4 * sizeof(float), stream);

    dim3 grid1(SPLIT, LB);
    gram_kernel<<<grid1, 256, 0, stream>>>(teacher, student, Gp, Sp);
    reduce_kernel<<<LB * NQ * 4, 256, 0, stream>>>(Gp, Sp, Acc);
    final_kernel<<<1, 64, 0, stream>>>(Acc, (float*)d_out);
}

// Round 7
// 78.077 us; speedup vs baseline: 1.0670x; 1.0582x over previous
//
#include <hip/hip_runtime.h>
#include <math.h>

// Problem constants: L=5, B=8, n=1024, d=64
#define LL 5
#define BB 8
#define NN 1024
#define DD 64
#define LB 40              // (l,b) pairs
#define SPLIT 16           // n-split: blocks per (l,b)
#define KC (NN / SPLIT)    // 64 k-rows per block
#define ZC (2 * DD)        // Z = [X | Y], 128 columns
#define NQ 3               // stored quadrants: 0=XX, 1=XY, 2=YY (YX dup skipped)

// Workspace (floats)
#define GP_SZ (LB * SPLIT * NQ * 4096)   // 7.86M floats (31.5 MB) partial quadrants
#define SP_SZ (LB * SPLIT * ZC)          // partial column sums
#define ACC_OFF (GP_SZ + SP_SZ)          // Acc2: LB x 3 x 4 segment sums

typedef short short8 __attribute__((ext_vector_type(8)));   // 8 bf16 = 4 VGPRs
typedef float floatx4 __attribute__((ext_vector_type(4)));  // MFMA C/D

__device__ __forceinline__ unsigned short f2bf(float f) {
    union { float f; unsigned u; } v; v.f = f;
    const unsigned u = v.u;
    return (unsigned short)((u + 0x7FFFu + ((u >> 16) & 1u)) >> 16);  // RNE
}
__device__ __forceinline__ float bf2f(unsigned short h) {
    union { unsigned u; float f; } v; v.u = ((unsigned)h) << 16; return v.f;
}

// LDS layout: bf16 K-major per Z-column, KC=64 (8 octets/col).
// Element (c,k) at short-index: c*64 + ((( (k>>3) ^ ((c + (c>>4)) & 15) ) & 7) << 3) + (k&7).
// Swizzle is uniform over bank groups for BOTH the b128 staging writes
// (c = 4*col4+e, fixed e: (4b+a+e) mod 8 spans all 8 as col4=4a+b varies) and
// the b128 frag reads (bijection in lane&15) -> conflict-free floor both ways.
__device__ __forceinline__ short8 read_frag(const short* Zt, int tbase, int lane, int k0) {
    const int c = tbase + (lane & 15);
    const int o = (k0 >> 3) + (lane >> 4);
    const int oct = (o ^ ((c + (c >> 4)) & 15)) & 7;
    return *(const short8*)(Zt + c * 64 + (oct << 3));
}

// Kernel 1: per-block partial gram of a 64-row slice of Z, via MFMA.
// grid (SPLIT, LB) x 256 thr (4 waves). Staging: 8 coalesced float4/thread
// (thread owns rows 8*rb..8*rb+7 = ONE k-octet), fp32->bf16 packed short8,
// 4 x ds_write_b128/thread. Wave w -> row-tiles {2w,2w+1} x all 8 col-tiles;
// YX duplicate quadrant never stored.
__global__ __launch_bounds__(256) void gram_kernel(const float* __restrict__ X,
                                                   const float* __restrict__ Y,
                                                   float* __restrict__ Gp,
                                                   float* __restrict__ Sp) {
    __shared__ short Zt[ZC * KC];      // 16 KB
    __shared__ float cscr[8][ZC];      // 4 KB col-sum scratch

    const int lb = blockIdx.y, nc = blockIdx.x, tid = threadIdx.x;
    const int r0 = nc * KC;
    const float4* X4 = (const float4*)(X + (size_t)lb * NN * DD);
    const float4* Y4 = (const float4*)(Y + (size_t)lb * NN * DD);

    // ---- load: 8 float4/thread, batched (all independent, in flight together)
    const int col4 = tid & 31;           // f4-column within the 32-f4 Z row
    const int rb = tid >> 5;             // 0..7: this thread's k-octet
    float4 v[8];
#pragma unroll
    for (int m = 0; m < 8; ++m) {
        const int row = 8 * rb + m;
        v[m] = (col4 < 16) ? X4[(size_t)(r0 + row) * 16 + col4]
                           : Y4[(size_t)(r0 + row) * 16 + (col4 - 16)];
    }

    // ---- convert + pack + 4 x b128 LDS writes + bf16-consistent col sums ----
#pragma unroll
    for (int e = 0; e < 4; ++e) {
        const int c = 4 * col4 + e;       // Z column 0..127
        short8 w8;
        float cs = 0.f;
#pragma unroll
        for (int m = 0; m < 8; ++m) {
            const float fv = (e == 0) ? v[m].x : (e == 1) ? v[m].y : (e == 2) ? v[m].z : v[m].w;
            const unsigned short b = f2bf(fv);
            cs += bf2f(b);
            w8[m] = (short)b;
        }
        const int oct = (rb ^ ((c + (c >> 4)) & 15)) & 7;
        *(short8*)(Zt + c * 64 + (oct << 3)) = w8;
        cscr[rb][c] = cs;
    }
    __syncthreads();
    if (tid < ZC) {
        float s = 0.f;
#pragma unroll
        for (int g = 0; g < 8; ++g) s += cscr[g][tid];
        Sp[(lb * SPLIT + nc) * ZC + tid] = s;
    }

    // ---- MFMA: wave w -> row-tiles {2w, 2w+1}, col-tiles 0..7, K=64 ----
    const int lane = tid & 63, w = tid >> 6;

    floatx4 acc[2][8];
#pragma unroll
    for (int i = 0; i < 2; ++i)
#pragma unroll
        for (int j = 0; j < 8; ++j) acc[i][j] = (floatx4){0.f, 0.f, 0.f, 0.f};

#pragma unroll
    for (int k0 = 0; k0 < KC; k0 += 32) {
        short8 af[2], bfr[8];
#pragma unroll
        for (int i = 0; i < 2; ++i) af[i] = read_frag(Zt, (2 * w + i) * 16, lane, k0);
#pragma unroll
        for (int j = 0; j < 8; ++j) bfr[j] = read_frag(Zt, j * 16, lane, k0);
#pragma unroll
        for (int i = 0; i < 2; ++i)
#pragma unroll
            for (int j = 0; j < 8; ++j)
                acc[i][j] = __builtin_amdgcn_mfma_f32_16x16x32_bf16(af[i], bfr[j], acc[i][j], 0, 0, 0);
    }

    // ---- store quadrant slabs: waves 0,1 = X rows (XX + XY); 2,3 = Y rows (YY only)
    float* Gb = Gp + (size_t)(lb * SPLIT + nc) * (NQ * 4096);
    const int g = lane >> 4, cl = lane & 15;
    if (w < 2) {
#pragma unroll
        for (int i = 0; i < 2; ++i)
#pragma unroll
            for (int j = 0; j < 8; ++j) {
                const int slab = (j < 4) ? 0 : 1;
                const int qcol = (j & 3) * 16 + cl;
#pragma unroll
                for (int r = 0; r < 4; ++r) {
                    const int qrow = (2 * w + i) * 16 + g * 4 + r;
                    Gb[slab * 4096 + qrow * 64 + qcol] = acc[i][j][r];
                }
            }
    } else {
#pragma unroll
        for (int i = 0; i < 2; ++i)
#pragma unroll
            for (int j = 4; j < 8; ++j) {
                const int qcol = (j - 4) * 16 + cl;
#pragma unroll
                for (int r = 0; r < 4; ++r) {
                    const int qrow = (2 * (w - 2) + i) * 16 + g * 4 + r;
                    Gb[2 * 4096 + qrow * 64 + qcol] = acc[i][j][r];
                }
            }
    }
}

// Kernel 2: sum SPLIT partials, center (Gc = G - s s^T / n), Frobenius-reduce.
// grid = LB*NQ*4 = 480 blocks x 256 thr; one f4/thread/partial; PLAIN store
// per block into its own Acc2 slot (no atomics -> no memset dispatch).
__global__ __launch_bounds__(256) void reduce_kernel(const float* __restrict__ Gp,
                                                     const float* __restrict__ Sp,
                                                     float* __restrict__ Acc2) {
    const int b = blockIdx.x;
    const int lb = b / (NQ * 4);
    const int rem = b % (NQ * 4);
    const int q = rem >> 2, seg = rem & 3;
    const int tid = threadIdx.x;

    __shared__ float stot[ZC];
    __shared__ float red[4];

    if (tid < ZC) {
        float s = 0.f;
#pragma unroll
        for (int sp = 0; sp < SPLIT; ++sp) s += Sp[(lb * SPLIT + sp) * ZC + tid];
        stot[tid] = s;
    }
    __syncthreads();

    const int idx0 = seg * 256 + tid;        // float4 index within 64x64 quadrant
    float4 g = make_float4(0.f, 0.f, 0.f, 0.f);
#pragma unroll
    for (int sp = 0; sp < SPLIT; ++sp) {
        const float4 p = *(const float4*)&Gp[((size_t)(lb * SPLIT + sp) * NQ + q) * 4096 + idx0 * 4];
        g.x += p.x; g.y += p.y; g.z += p.z; g.w += p.w;
    }
    const int row = idx0 >> 4, col0 = (idx0 & 15) * 4;
    const int rowbase = (q == 2) ? 64 : 0;   // quadrant rows: Y for YY
    const int colbase = (q == 0) ? 0 : 64;   // quadrant cols: X only for XX
    const float inv_n = 1.0f / (float)NN;
    const float srow = stot[rowbase + row] * inv_n;
    const float ga[4] = {g.x, g.y, g.z, g.w};
    float sq = 0.f;
#pragma unroll
    for (int e = 0; e < 4; ++e) {
        const float cv = ga[e] - srow * stot[colbase + col0 + e];
        sq += cv * cv;
    }
#pragma unroll
    for (int off = 32; off; off >>= 1) sq += __shfl_down(sq, off);
    const int wave = tid >> 6;
    if ((tid & 63) == 0) red[wave] = sq;
    __syncthreads();
    if (tid == 0)
        Acc2[lb * 12 + q * 4 + seg] = red[0] + red[1] + red[2] + red[3];
}

// Kernel 3: sum segments, ratio, loss = mean_l(-log(mean_b(ratio)+eps))
__global__ void final_kernel(const float* __restrict__ Acc2, float* __restrict__ out) {
    const int tid = threadIdx.x;   // one wave
    float v = 0.0f;
    if (tid < LB) {
        float vxx = 0.f, hxy = 0.f, vyy = 0.f;
#pragma unroll
        for (int s = 0; s < 4; ++s) {
            vxx += Acc2[tid * 12 + s];
            hxy += Acc2[tid * 12 + 4 + s];
            vyy += Acc2[tid * 12 + 8 + s];
        }
        v = fabsf(hxy / (sqrtf(vxx) * sqrtf(vyy)));
    }
    v += __shfl_xor(v, 1);
    v += __shfl_xor(v, 2);
    v += __shfl_xor(v, 4);
    float loss = 0.0f;
#pragma unroll
    for (int l = 0; l < LL; ++l) {
        const float sl = __shfl(v, l * BB);
        loss += -logf(sl * (1.0f / (float)BB) + 1e-8f);
    }
    if (tid == 0) out[0] = loss * (1.0f / (float)LL);
}

extern "C" void kernel_launch(void* const* d_in, const int* in_sizes, int n_in,
                              void* d_out, int out_size, void* d_ws, size_t ws_size,
                              hipStream_t stream) {
    const float* teacher = (const float*)d_in[0];
    const float* student = (const float*)d_in[1];
    float* ws = (float*)d_ws;
    float* Gp = ws;
    float* Sp = ws + GP_SZ;
    float* Acc2 = ws + ACC_OFF;

    dim3 grid1(SPLIT, LB);
    gram_kernel<<<grid1, 256, 0, stream>>>(teacher, student, Gp, Sp);
    reduce_kernel<<<LB * NQ * 4, 256, 0, stream>>>(Gp, Sp, Acc2);
    final_kernel<<<1, 64, 0, stream>>>(Acc2, (float*)d_out);
}

// Round 8
// 77.296 us; speedup vs baseline: 1.0778x; 1.0101x over previous
//
#include <hip/hip_runtime.h>
#include <math.h>

// Problem constants: L=5, B=8, n=1024, d=64
#define LL 5
#define BB 8
#define NN 1024
#define DD 64
#define LB 40              // (l,b) pairs
#define SPLIT 16           // n-split: blocks per (l,b)
#define KC (NN / SPLIT)    // 64 k-rows per block
#define ZC (2 * DD)        // Z = [X | Y], 128 columns
#define NQ 3               // stored quadrants: 0=XX, 1=XY, 2=YY (YX dup skipped)

// Workspace layout
// Gp: bf16 partial quadrants, LB*SPLIT*NQ*4096 shorts = 15.7 MB
// Quadrant element (row,col) -> short index (row>>1)*128 + col*2 + (row&1)
// (row-pairs packed per dword so the C/D reg pairs store as single dwords).
#define GP_SHORTS (LB * SPLIT * NQ * 4096)
#define GP_FLOATS (GP_SHORTS / 2)
#define SP_OFF GP_FLOATS                   // Sp: LB*SPLIT*ZC floats
#define ACC_OFF (GP_FLOATS + LB * SPLIT * ZC)  // Acc2: LB x 3 x 4 segment sums

typedef short short8 __attribute__((ext_vector_type(8)));   // 8 bf16 = 4 VGPRs
typedef float floatx4 __attribute__((ext_vector_type(4)));  // MFMA C/D

__device__ __forceinline__ unsigned short f2bf(float f) {
    union { float f; unsigned u; } v; v.f = f;
    const unsigned u = v.u;
    return (unsigned short)((u + 0x7FFFu + ((u >> 16) & 1u)) >> 16);  // RNE
}
__device__ __forceinline__ float bf2f(unsigned short h) {
    union { unsigned u; float f; } v; v.u = ((unsigned)h) << 16; return v.f;
}
__device__ __forceinline__ float bflo(unsigned u) {
    union { unsigned u; float f; } v; v.u = u << 16; return v.f;
}
__device__ __forceinline__ float bfhi(unsigned u) {
    union { unsigned u; float f; } v; v.u = u & 0xFFFF0000u; return v.f;
}

// LDS: bf16 K-major per Z-column, KC=64 (8 octets/col).
// Element (c,k) at short-index: c*64 + ((((k>>3) ^ ((c+(c>>4)) & 15)) & 7) << 3) + (k&7).
// Conflict-free for both b128 staging writes and b128 frag reads (R7-verified).
__device__ __forceinline__ short8 read_frag(const short* Zt, int tbase, int lane, int k0) {
    const int c = tbase + (lane & 15);
    const int o = (k0 >> 3) + (lane >> 4);
    const int oct = (o ^ ((c + (c >> 4)) & 15)) & 7;
    return *(const short8*)(Zt + c * 64 + (oct << 3));
}

// Kernel 1: per-block partial gram of a 64-row slice of Z via MFMA.
// grid (SPLIT, LB) x 256 thr (4 waves). Waves 0,1: X row-tiles x all 8 col-tiles
// (XX + XY). Waves 2,3: Y row-tiles x Y col-tiles only (YY) — YX never computed.
// Partials stored bf16, row-pair packed.
__global__ __launch_bounds__(256) void gram_kernel(const float* __restrict__ X,
                                                   const float* __restrict__ Y,
                                                   unsigned* __restrict__ Gp,
                                                   float* __restrict__ Sp) {
    __shared__ short Zt[ZC * KC];      // 16 KB
    __shared__ float cscr[8][ZC];      // 4 KB col-sum scratch

    const int lb = blockIdx.y, nc = blockIdx.x, tid = threadIdx.x;
    const int r0 = nc * KC;
    const float4* X4 = (const float4*)(X + (size_t)lb * NN * DD);
    const float4* Y4 = (const float4*)(Y + (size_t)lb * NN * DD);

    // ---- load: 8 coalesced float4/thread; thread owns one k-octet ----
    const int col4 = tid & 31;
    const int rb = tid >> 5;
    float4 v[8];
#pragma unroll
    for (int m = 0; m < 8; ++m) {
        const int row = 8 * rb + m;
        v[m] = (col4 < 16) ? X4[(size_t)(r0 + row) * 16 + col4]
                           : Y4[(size_t)(r0 + row) * 16 + (col4 - 16)];
    }

    // ---- convert + pack + 4 x b128 LDS writes + bf16-consistent col sums ----
#pragma unroll
    for (int e = 0; e < 4; ++e) {
        const int c = 4 * col4 + e;
        short8 w8;
        float cs = 0.f;
#pragma unroll
        for (int m = 0; m < 8; ++m) {
            const float fv = (e == 0) ? v[m].x : (e == 1) ? v[m].y : (e == 2) ? v[m].z : v[m].w;
            const unsigned short b = f2bf(fv);
            cs += bf2f(b);
            w8[m] = (short)b;
        }
        const int oct = (rb ^ ((c + (c >> 4)) & 15)) & 7;
        *(short8*)(Zt + c * 64 + (oct << 3)) = w8;
        cscr[rb][c] = cs;
    }
    __syncthreads();
    if (tid < ZC) {
        float s = 0.f;
#pragma unroll
        for (int g = 0; g < 8; ++g) s += cscr[g][tid];
        Sp[(lb * SPLIT + nc) * ZC + tid] = s;
    }

    // ---- MFMA ----
    const int lane = tid & 63, w = tid >> 6;
    const int jbeg = (w < 2) ? 0 : 4;     // upper waves skip YX col-tiles

    floatx4 acc[2][8];
#pragma unroll
    for (int i = 0; i < 2; ++i)
#pragma unroll
        for (int j = 0; j < 8; ++j) acc[i][j] = (floatx4){0.f, 0.f, 0.f, 0.f};

#pragma unroll
    for (int k0 = 0; k0 < KC; k0 += 32) {
        short8 af[2], bfr[8];
#pragma unroll
        for (int i = 0; i < 2; ++i) af[i] = read_frag(Zt, (2 * w + i) * 16, lane, k0);
#pragma unroll
        for (int j = 0; j < 8; ++j)
            if (j >= jbeg) bfr[j] = read_frag(Zt, j * 16, lane, k0);
#pragma unroll
        for (int i = 0; i < 2; ++i)
#pragma unroll
            for (int j = 0; j < 8; ++j)
                if (j >= jbeg)
                    acc[i][j] = __builtin_amdgcn_mfma_f32_16x16x32_bf16(af[i], bfr[j], acc[i][j], 0, 0, 0);
    }

    // ---- store bf16 row-pair-packed partial quadrants ----
    // C/D: col = lane&15, row = (lane>>4)*4 + r. Rows g*4+{0,1}, g*4+{2,3} pack.
    unsigned* Gb = Gp + (size_t)(lb * SPLIT + nc) * (NQ * 2048);
    const int g = lane >> 4, cl = lane & 15;
#pragma unroll
    for (int i = 0; i < 2; ++i)
#pragma unroll
        for (int j = 0; j < 8; ++j) {
            if (j < jbeg) continue;
            const int slab = (w < 2) ? ((j < 4) ? 0 : 1) : 2;
            const int qrow0 = (w < 2 ? (2 * w + i) : (2 * (w - 2) + i)) * 16 + g * 4;
            const int qcol = (j & 3) * 16 + cl;
            if (w < 2 || j >= 4) {
                const unsigned lo = (unsigned)f2bf(acc[i][j][0]) | ((unsigned)f2bf(acc[i][j][1]) << 16);
                const unsigned hi = (unsigned)f2bf(acc[i][j][2]) | ((unsigned)f2bf(acc[i][j][3]) << 16);
                Gb[slab * 2048 + (qrow0 >> 1) * 64 + qcol] = lo;
                Gb[slab * 2048 + ((qrow0 >> 1) + 1) * 64 + qcol] = hi;
            }
        }
}

// Kernel 2: sum SPLIT bf16 partials, center (Gc = G - s s^T/n), Frobenius-reduce.
// grid = LB*NQ*4 = 480 blocks x 256 thr. Thread handles one uint2 = 2 cols x 2 rows
// per partial. Plain store per block into its own Acc2 slot.
__global__ __launch_bounds__(256) void reduce_kernel(const unsigned* __restrict__ Gp,
                                                     const float* __restrict__ Sp,
                                                     float* __restrict__ Acc2) {
    const int b = blockIdx.x;
    const int lb = b / (NQ * 4);
    const int rem = b % (NQ * 4);
    const int q = rem >> 2, seg = rem & 3;
    const int tid = threadIdx.x;

    __shared__ float stot[ZC];
    __shared__ float red[4];

    if (tid < ZC) {
        float s = 0.f;
#pragma unroll
        for (int sp = 0; sp < SPLIT; ++sp) s += Sp[(lb * SPLIT + sp) * ZC + tid];
        stot[tid] = s;
    }
    __syncthreads();

    const int u0 = seg * 512 + tid * 2;      // uint index within 2048-uint quadrant
    const int rp = u0 >> 6;                  // row-pair
    const int c0 = u0 & 63;                  // column (c0, c0+1)

    float g00 = 0.f, g10 = 0.f, g01 = 0.f, g11 = 0.f;   // [row&1][col-e]
#pragma unroll
    for (int sp = 0; sp < SPLIT; ++sp) {
        const uint2 p = *(const uint2*)&Gp[((size_t)(lb * SPLIT + sp) * NQ + q) * 2048 + u0];
        g00 += bflo(p.x); g10 += bfhi(p.x);
        g01 += bflo(p.y); g11 += bfhi(p.y);
    }
    const int rowbase = (q == 2) ? 64 : 0;
    const int colbase = (q == 0) ? 0 : 64;
    const float inv_n = 1.0f / (float)NN;
    const float sr0 = stot[rowbase + 2 * rp] * inv_n;
    const float sr1 = stot[rowbase + 2 * rp + 1] * inv_n;
    const float sc0 = stot[colbase + c0];
    const float sc1 = stot[colbase + c0 + 1];
    float sq = 0.f;
    { const float cv = g00 - sr0 * sc0; sq += cv * cv; }
    { const float cv = g10 - sr1 * sc0; sq += cv * cv; }
    { const float cv = g01 - sr0 * sc1; sq += cv * cv; }
    { const float cv = g11 - sr1 * sc1; sq += cv * cv; }

#pragma unroll
    for (int off = 32; off; off >>= 1) sq += __shfl_down(sq, off);
    const int wave = tid >> 6;
    if ((tid & 63) == 0) red[wave] = sq;
    __syncthreads();
    if (tid == 0)
        Acc2[lb * 12 + q * 4 + seg] = red[0] + red[1] + red[2] + red[3];
}

// Kernel 3: sum segments, ratio, loss = mean_l(-log(mean_b(ratio)+eps))
__global__ void final_kernel(const float* __restrict__ Acc2, float* __restrict__ out) {
    const int tid = threadIdx.x;   // one wave
    float v = 0.0f;
    if (tid < LB) {
        float vxx = 0.f, hxy = 0.f, vyy = 0.f;
#pragma unroll
        for (int s = 0; s < 4; ++s) {
            vxx += Acc2[tid * 12 + s];
            hxy += Acc2[tid * 12 + 4 + s];
            vyy += Acc2[tid * 12 + 8 + s];
        }
        v = fabsf(hxy / (sqrtf(vxx) * sqrtf(vyy)));
    }
    v += __shfl_xor(v, 1);
    v += __shfl_xor(v, 2);
    v += __shfl_xor(v, 4);
    float loss = 0.0f;
#pragma unroll
    for (int l = 0; l < LL; ++l) {
        const float sl = __shfl(v, l * BB);
        loss += -logf(sl * (1.0f / (float)BB) + 1e-8f);
    }
    if (tid == 0) out[0] = loss * (1.0f / (float)LL);
}

extern "C" void kernel_launch(void* const* d_in, const int* in_sizes, int n_in,
                              void* d_out, int out_size, void* d_ws, size_t ws_size,
                              hipStream_t stream) {
    const float* teacher = (const float*)d_in[0];
    const float* student = (const float*)d_in[1];
    float* ws = (float*)d_ws;
    unsigned* Gp = (unsigned*)ws;
    float* Sp = ws + SP_OFF;
    float* Acc2 = ws + ACC_OFF;

    dim3 grid1(SPLIT, LB);
    gram_kernel<<<grid1, 256, 0, stream>>>(teacher, student, Gp, Sp);
    reduce_kernel<<<LB * NQ * 4, 256, 0, stream>>>(Gp, Sp, Acc2);
    final_kernel<<<1, 64, 0, stream>>>(Acc2, (float*)d_out);
}